// Round 7
// baseline (13452.576 us; speedup 1.0000x reference)
//
#include <hip/hip_runtime.h>
#include <hip/hip_bf16.h>

typedef __bf16 bf16x8 __attribute__((ext_vector_type(8)));
typedef float f32x4 __attribute__((ext_vector_type(4)));
typedef unsigned int u32;
typedef u32 u32x4 __attribute__((ext_vector_type(4)));

#define MFMA_B16(a,b,c) __builtin_amdgcn_mfma_f32_16x16x32_bf16((a),(b),(c),0,0,0)

// Tsit5 coefficients
#define A21f 0.161f
#define A31f (-0.008480655492356989f)
#define A32f 0.335480655492357f
#define A41f 2.8971530571054935f
#define A42f (-6.359448489975075f)
#define A43f 4.3622954328695815f
#define A51f 5.325864828439257f
#define A52f (-11.748883564062828f)
#define A53f 7.4955393428898365f
#define A54f (-0.09249506636175525f)
#define A61f 5.86145544294642f
#define A62f (-12.92096931784711f)
#define A63f 8.159367898576159f
#define A64f (-0.071584973281401f)
#define A65f (-0.028269050394068383f)
#define B1f 0.09646076681806523f
#define B2f 0.01f
#define B3f 0.4798896504144996f
#define B4f 1.379008574103742f
#define B5f (-3.290069515436081f)
#define B6f 2.324710524099774f

constexpr int T_SAVE = 128;
constexpr int DIM = 64;
constexpr int HID = 256;

__device__ __forceinline__ float fast_exp2(float x){
#if __has_builtin(__builtin_amdgcn_exp2f)
  return __builtin_amdgcn_exp2f(x);
#else
  return exp2f(x);
#endif
}
__device__ __forceinline__ float fast_rcp(float x){
#if __has_builtin(__builtin_amdgcn_rcpf)
  return __builtin_amdgcn_rcpf(x);
#else
  return 1.0f / x;
#endif
}
__device__ __forceinline__ float tanh_fast(float x){
  float t = fast_exp2(x * 2.8853900817779268f);
  return 1.0f - 2.0f * fast_rcp(t + 1.0f);
}
__device__ __forceinline__ f32x4 splat4(float x){ return f32x4{x,x,x,x}; }

// pack: low16 = hi-bf16 (mantissa truncation), high16 = lo-bf16 (RNE of residual)
__device__ __forceinline__ u32 pack_hl(float x){
  u32 xu = __float_as_uint(x);
  float lo = x - __uint_as_float(xu & 0xFFFF0000u);
  __bf16 lb = (__bf16)lo;
  unsigned short ls; __builtin_memcpy(&ls, &lb, 2);
  return ((u32)ls << 16) | (xu >> 16);
}
// 8 packed dwords (ascending k) -> hi-frag and lo-frag bf16x8
__device__ __forceinline__ void unpack2(const u32* p, bf16x8& ah, bf16x8& al){
  union { u32 d[4]; bf16x8 v; } H, L;
#pragma unroll
  for (int j = 0; j < 4; ++j) {
    H.d[j] = __builtin_amdgcn_perm(p[2*j+1], p[2*j], 0x05040100u);
    L.d[j] = __builtin_amdgcn_perm(p[2*j+1], p[2*j], 0x07060302u);
  }
  ah = H.v; al = L.v;
}

// 4-dword block (row, kq) within a K-slice; bphys%8 = (row&7)^(kq&7):
// conflict-free reads (verified R6: SQ_LDS_BANK_CONFLICT = 0) and free 2-way writes.
__device__ __forceinline__ int bphys(int row, int kq){
  return kq*16 + (row & 8) + ((row & 7) ^ (kq & 7));
}

// Barrier-free producer-consumer pipeline. 8 waves (512 thr)/block, 16 rows/block.
// Waves 0-3 (MLP, v=w): flat loop over ALL fevals n: poll Y(n), compute L1 tiles
//   T = v+4t (6 MFMA each) + tanh, write packed H(n), publish hctr[T]=n+1.
// Waves 4-7 (STATE, v=w-4): own RK state for dims v*16..v*16+15; per feval:
//   per-slice poll hctr, full-K L2 (24 MFMA), RK update, stage packed Y(n+1),
//   publish yctr[v]=n+2. Monotonic epoch counters, parity double-buffering.
__global__ __launch_bounds__(512, 2)
void node_tsit5_kernel(const float* __restrict__ y0, const float* __restrict__ ts,
                       const float* __restrict__ W1g, const float* __restrict__ b1g,
                       const float* __restrict__ W2g, const float* __restrict__ b2g,
                       const int* __restrict__ nsub_p, float* __restrict__ out)
{
  const int tid = (int)threadIdx.x;
  const int w   = tid >> 6;   // wave 0..7
  const int l   = tid & 63;
  const int c   = l & 15;
  const int g   = l >> 4;
  const bool stateRole = (w >= 4);
  const int v   = w & 3;
  const int rowbase = (int)blockIdx.x * 16;

  __shared__ __align__(16) u32 Yp[2][1024];   // [parity][2 slices x 512 dwords]
  __shared__ __align__(16) u32 Hp[2][4096];   // [parity][8 slices x 512 dwords]
  __shared__ u32 yctr[4];                     // state wave v: Y epoch ready
  __shared__ u32 hctr[16];                    // mlp tile T: H epoch ready
  __shared__ float ts_s[T_SAVE];

  if (tid < T_SAVE) ts_s[tid] = ts[tid];
  if (tid < 16) hctr[tid] = 0;
  if (tid < 4)  yctr[tid] = 0;

  const int nsub = nsub_p[0];
  const u32 NF = (u32)(T_SAVE - 1) * (u32)nsub * 6u;

  // shared read addressing (both roles): lane (c,g) reads blocks kq=2g,2g+1
  const int rdw0 = bphys(c, 2*g    ) * 4;
  const int rdw1 = bphys(c, 2*g + 1) * 4;

  __syncthreads();   // ts_s + counters initialized; only block-wide barrier

  if (!stateRole) {
    // ================= MLP producer =================
    bf16x8 wh[4][2], wl[4][2];
    float b1v[4];
    int hw_[4][4];
#pragma unroll
    for (int t = 0; t < 4; ++t) {
      const int T = v + 4*t;
      const int col = T*16 + c;
#pragma unroll
      for (int sl = 0; sl < 2; ++sl)
#pragma unroll
        for (int j = 0; j < 8; ++j) {
          float val = W1g[(sl*32 + g*8 + j)*HID + col];
          __bf16 hi = (__bf16)val;
          wh[t][sl][j] = hi;
          wl[t][sl][j] = (__bf16)(val - (float)hi);
        }
      b1v[t] = b1g[col];
      const int kq = (T & 1)*4 + (c >> 2);
#pragma unroll
      for (int r = 0; r < 4; ++r)
        hw_[t][r] = (T >> 1)*512 + bphys(4*g + r, kq)*4 + (c & 3);
    }

    volatile u32* yc = yctr;
    for (u32 n = 0; n < NF; ++n) {
      const u32 need = n + 1u;
      while (yc[0] < need || yc[1] < need || yc[2] < need || yc[3] < need)
        __builtin_amdgcn_s_sleep(1);
      asm volatile("" ::: "memory");        // fence: no data-load hoist above poll
      const u32* Yb = Yp[n & 1];
      u32 py[8], pz[8];
      *(u32x4*)&py[0] = *(const u32x4*)&Yb[rdw0];
      *(u32x4*)&py[4] = *(const u32x4*)&Yb[rdw1];
      *(u32x4*)&pz[0] = *(const u32x4*)&Yb[512 + rdw0];
      *(u32x4*)&pz[4] = *(const u32x4*)&Yb[512 + rdw1];
      bf16x8 ah0, al0, ah1, al1;
      unpack2(py, ah0, al0);
      unpack2(pz, ah1, al1);
      u32* Hb = Hp[n & 1];
#pragma unroll
      for (int t = 0; t < 4; ++t) {
        f32x4 a0 = {0.f,0.f,0.f,0.f}, a1 = {0.f,0.f,0.f,0.f};
        a0 = MFMA_B16(ah0, wh[t][0], a0);  a1 = MFMA_B16(ah1, wh[t][1], a1);
        a0 = MFMA_B16(ah0, wl[t][0], a0);  a1 = MFMA_B16(ah1, wl[t][1], a1);
        a0 = MFMA_B16(al0, wh[t][0], a0);  a1 = MFMA_B16(al1, wh[t][1], a1);
        f32x4 ht = a0 + a1;
#pragma unroll
        for (int r = 0; r < 4; ++r)
          Hb[hw_[t][r]] = pack_hl(tanh_fast(ht[r] + b1v[t]));
        asm volatile("s_waitcnt lgkmcnt(0)" ::: "memory");  // H data visible
        if (l == 0) *(volatile u32*)&hctr[v + 4*t] = need;
      }
    }
  } else {
    // ================= STATE consumer =================
    bf16x8 w2h[8], w2l[8];
#pragma unroll
    for (int ks = 0; ks < 8; ++ks)
#pragma unroll
      for (int j = 0; j < 8; ++j) {
        float val = W2g[(ks*32 + g*8 + j)*DIM + (v*16 + c)];
        __bf16 hi = (__bf16)val;
        w2h[ks][j] = hi;
        w2l[ks][j] = (__bf16)(val - (float)hi);
      }
    const float b2v = b2g[v*16 + c];
    const int d_ = v*16 + c;

    int yw[4];
#pragma unroll
    for (int s4 = 0; s4 < 4; ++s4) {
      const int kq = (v & 1)*4 + (c >> 2);
      yw[s4] = (v >> 1)*512 + bphys(4*g + s4, kq)*4 + (c & 3);
    }

    f32x4 y4;
#pragma unroll
    for (int s4 = 0; s4 < 4; ++s4) {
      int row = rowbase + 4*g + s4;
      y4[s4] = y0[row*DIM + d_];
      out[(size_t)row*(T_SAVE*DIM) + d_] = y4[s4];
    }

    auto stage = [&](const f32x4& val, u32 n){
      u32* Yb = Yp[n & 1];
#pragma unroll
      for (int s4 = 0; s4 < 4; ++s4) Yb[yw[s4]] = pack_hl(val[s4]);
      asm volatile("s_waitcnt lgkmcnt(0)" ::: "memory");    // Y data visible
      if (l == 0) *(volatile u32*)&yctr[v] = n + 1u;
    };

    auto consume = [&](u32 n) -> f32x4 {
      const u32* Hb = Hp[n & 1];
      const u32 need = n + 1u;
      f32x4 aA = {0.f,0.f,0.f,0.f}, aB = {0.f,0.f,0.f,0.f}, aC = {0.f,0.f,0.f,0.f};
#pragma unroll
      for (int ks = 0; ks < 8; ++ks) {
        volatile u32* hc = &hctr[2*ks];
        while (hc[0] < need || hc[1] < need) __builtin_amdgcn_s_sleep(1);
        asm volatile("" ::: "memory");      // fence: no data-load hoist above poll
        u32 ph[8];
        *(u32x4*)&ph[0] = *(const u32x4*)&Hb[ks*512 + rdw0];
        *(u32x4*)&ph[4] = *(const u32x4*)&Hb[ks*512 + rdw1];
        bf16x8 ah, al;
        unpack2(ph, ah, al);
        aA = MFMA_B16(ah, w2h[ks], aA);
        aB = MFMA_B16(ah, w2l[ks], aB);
        aC = MFMA_B16(al, w2h[ks], aC);
      }
      return (aA + aB) + aC + splat4(b2v);
    };

    f32x4 ysv = y4;
    stage(ysv, 0);                           // Y(0) ready -> pipeline starts
    u32 ep = 0;

    for (int iv = 0; iv < T_SAVE-1; ++iv) {
      const float h = (ts_s[iv+1] - ts_s[iv]) / (float)nsub;
      const f32x4 h4 = splat4(h);
      for (int sub = 0; sub < nsub; ++sub) {
        f32x4 k1 = consume(ep);
        ysv = y4 + h4 * (splat4(A21f) * k1);
        stage(ysv, ep+1); ++ep;
        f32x4 k2 = consume(ep);
        {
          f32x4 t = splat4(A31f)*k1 + splat4(A32f)*k2;
          ysv = y4 + h4 * t;
        }
        stage(ysv, ep+1); ++ep;
        f32x4 k3 = consume(ep);
        {
          f32x4 t = splat4(A41f)*k1 + splat4(A42f)*k2 + splat4(A43f)*k3;
          ysv = y4 + h4 * t;
        }
        stage(ysv, ep+1); ++ep;
        f32x4 k4 = consume(ep);
        {
          f32x4 t = splat4(A51f)*k1 + splat4(A52f)*k2 + splat4(A53f)*k3
                  + splat4(A54f)*k4;
          ysv = y4 + h4 * t;
        }
        stage(ysv, ep+1); ++ep;
        f32x4 k5 = consume(ep);
        {
          f32x4 t = splat4(A61f)*k1 + splat4(A62f)*k2 + splat4(A63f)*k3
                  + splat4(A64f)*k4 + splat4(A65f)*k5;
          ysv = y4 + h4 * t;
        }
        stage(ysv, ep+1); ++ep;
        f32x4 k6 = consume(ep);
        {
          f32x4 t = splat4(B1f)*k1 + splat4(B2f)*k2 + splat4(B3f)*k3
                  + splat4(B4f)*k4 + splat4(B5f)*k5 + splat4(B6f)*k6;
          y4 = y4 + h4 * t;
          ysv = y4;
        }
        stage(ysv, ep+1); ++ep;              // final stage past NF is harmless
      }
#pragma unroll
      for (int s4 = 0; s4 < 4; ++s4) {
        int row = rowbase + 4*g + s4;
        out[(size_t)row*(T_SAVE*DIM) + (size_t)(iv+1)*DIM + d_] = y4[s4];
      }
    }
  }
}

extern "C" void kernel_launch(void* const* d_in, const int* in_sizes, int n_in,
                              void* d_out, int out_size, void* d_ws, size_t ws_size,
                              hipStream_t stream) {
  const float* y0 = (const float*)d_in[0];
  const float* ts = (const float*)d_in[1];
  const float* W1 = (const float*)d_in[2];
  const float* b1 = (const float*)d_in[3];
  const float* W2 = (const float*)d_in[4];
  const float* b2 = (const float*)d_in[5];
  const int* nsub = (const int*)d_in[6];
  float* out = (float*)d_out;

  const int Bnum = in_sizes[0] / DIM;       // 4096
  const int nblocks = Bnum / 16;            // 256 workgroups, one per CU
  node_tsit5_kernel<<<nblocks, 512, 0, stream>>>(y0, ts, W1, b1, W2, b2, nsub, out);
}